// Round 6
// baseline (465.784 us; speedup 1.0000x reference)
//
#include <hip/hip_runtime.h>
#include <stdint.h>
#include <math.h>

#define D_MODEL 1024
#define D_INNER 2048
#define N_RES   1024
#define SEQ     4096
#define BATCH   4
#define M_TOT   (BATCH*SEQ)   // 16384
#define SMEM_BYTES 73728

typedef float f32x4 __attribute__((ext_vector_type(4)));
typedef short bf16x8 __attribute__((ext_vector_type(8)));
typedef unsigned short u16;

__device__ __forceinline__ u16 f2bf(float f) {
  uint32_t u = __builtin_bit_cast(uint32_t, f);
  u += 0x7FFFu + ((u >> 16) & 1u);   // RNE
  return (u16)(u >> 16);
}
__device__ __forceinline__ float bf2f(u16 h) {
  return __builtin_bit_cast(float, (uint32_t)h << 16);
}

__device__ __forceinline__ void g2l16(const void* g, void* l) {
  __builtin_amdgcn_global_load_lds(
      (const __attribute__((address_space(1))) void*)g,
      (__attribute__((address_space(3))) void*)l, 16, 0, 0);
}

// ---------------- f32 -> bf16 convert ----------------
__global__ void cvt_kernel(const float* __restrict__ src, u16* __restrict__ dst, int n4) {
  int stride = gridDim.x * blockDim.x;
  for (int i = blockIdx.x * blockDim.x + threadIdx.x; i < n4; i += stride) {
    f32x4 v = *(const f32x4*)(src + (size_t)i * 4);
    ushort4 o;
    o.x = f2bf(v.x); o.y = f2bf(v.y); o.z = f2bf(v.z); o.w = f2bf(v.w);
    *(ushort4*)(dst + (size_t)i * 4) = o;
  }
}

// ---------------- 256x128 bf16 GEMM, C = A @ B^T ----------------
// 256 threads (4 waves 2Mx2N), BK=32, TRIPLE-buffered LDS (72 KB) -> 2 blocks/CU:
// two independent barrier domains per CU; when one block waits at vmcnt/barrier
// the other feeds MFMA+LDS pipes (m114 implicit overlap). Register-pipelined
// (READ t+1 under MFMA t), stage-ahead-2, counted vmcnt(6). T2 swizzle both-sides.
template<int EPI, int K, int NBX>
__global__ __launch_bounds__(256, 2) void gemm128(
    const u16* __restrict__ A, const u16* __restrict__ B,
    void* __restrict__ out0, void* __restrict__ out1,
    const float* __restrict__ bias)
{
  extern __shared__ char smem[];   // A: 3x16KB @0 ; B: 3x8KB @49152
  constexpr int NT = K / 32;
  const int tid  = threadIdx.x;
  const int lane = tid & 63;
  const int wave = tid >> 6;       // 0..3
  const int wm = wave >> 1, wn = wave & 1;

  // XCD-bijective remap (grid % 8 == 0)
  const int nb  = (M_TOT / 256) * NBX;
  const int cpx = nb >> 3;
  const int wg  = ((int)blockIdx.x & 7) * cpx + ((int)blockIdx.x >> 3);
  const int m0 = (wg / NBX) << 8;
  const int n0 = (wg % NBX) << 7;

  // staging: per g2l16 a wave covers 16 rows x 32k (1024 B LDS linear).
  // A: 4 instrs/wave (rows wave*64 + i*16 + lane>>2); B: 2 instrs (rows wave*32 + ...).
  const int st_row = lane >> 2;
  const int st_kc  = (((lane & 3) ^ ((lane >> 3) & 3)) << 3);  // pre-swizzled k-chunk
  const u16* pA = A + (size_t)(m0 + (wave << 6) + st_row) * K + st_kc;
  const u16* pB = B + (size_t)(n0 + (wave << 5) + st_row) * K + st_kc;
  const int stA = wave << 12;   // 64 rows * 64 B
  const int stB = wave << 11;   // 32 rows * 64 B

  // fragment read offsets (row stride 64 B, swizzled 16B chunk)
  const int l15 = lane & 15, k16 = lane >> 4;
  const int chunk = ((k16 ^ ((l15 >> 1) & 3)) << 4);
  const int aoff = (((wm << 7) + l15) << 6) + chunk;
  const int boff = (((wn << 6) + l15) << 6) + chunk;

  f32x4 acc[8][4] = {};
  bf16x8 aP[8], bP[4], aQ[8], bQ[4];

  char* A0 = smem;          char* B0 = smem + 49152;
  char* A1 = smem + 16384;  char* B1 = smem + 57344;
  char* A2 = smem + 32768;  char* B2 = smem + 65536;

#define STAGE(ts_, AB_, BB_) do {                          \
    const int kt_ = (ts_) << 5;                            \
    _Pragma("unroll")                                      \
    for (int i_ = 0; i_ < 4; ++i_)                         \
      g2l16(pA + (size_t)(i_ << 4) * K + kt_, (AB_) + stA + (i_ << 10)); \
    _Pragma("unroll")                                      \
    for (int i_ = 0; i_ < 2; ++i_)                         \
      g2l16(pB + (size_t)(i_ << 4) * K + kt_, (BB_) + stB + (i_ << 10)); \
  } while (0)

#define READF(AB_, BB_, RA_, RB_) do {                              \
    _Pragma("unroll")                                               \
    for (int i_ = 0; i_ < 8; ++i_)                                  \
      RA_[i_] = *(const bf16x8*)((AB_) + aoff + (i_ << 10));        \
    _Pragma("unroll")                                               \
    for (int j_ = 0; j_ < 4; ++j_)                                  \
      RB_[j_] = *(const bf16x8*)((BB_) + boff + (j_ << 10));        \
  } while (0)

#define MFMA32(MA_, MB_) do {                                       \
    __builtin_amdgcn_sched_barrier(0);                              \
    __builtin_amdgcn_s_setprio(1);                                  \
    _Pragma("unroll")                                               \
    for (int j_ = 0; j_ < 4; ++j_) {                                \
      _Pragma("unroll")                                             \
      for (int i_ = 0; i_ < 8; ++i_)                                \
        acc[i_][j_] = __builtin_amdgcn_mfma_f32_16x16x32_bf16(MA_[i_], MB_[j_], acc[i_][j_], 0, 0, 0); \
    }                                                               \
    __builtin_amdgcn_s_setprio(0);                                  \
    __builtin_amdgcn_sched_barrier(0);                              \
  } while (0)

  // prologue: stage tiles 0,1 (12 gloads/wave); drain tile 0; read its frags
  STAGE(0, A0, B0);
  STAGE(1, A1, B1);
  asm volatile("s_waitcnt vmcnt(6)" ::: "memory");
  __builtin_amdgcn_s_barrier();
  READF(A0, B0, aP, bP);

  // main: unguarded pairs; phase u: {STAGE(u+2); vmcnt(6) drains u+1; barrier;
  // READ(u+1); MFMA(u)}.  (NT even; last main pair stages NT-3.)
  for (int t = 0; t < NT - 4; t += 2) {
    STAGE(t + 2, A2, B2);
    asm volatile("s_waitcnt vmcnt(6)" ::: "memory");
    __builtin_amdgcn_s_barrier();
    READF(A1, B1, aQ, bQ);
    MFMA32(aP, bP);

    STAGE(t + 3, A0, B0);
    asm volatile("s_waitcnt vmcnt(6)" ::: "memory");
    __builtin_amdgcn_s_barrier();
    READF(A2, B2, aP, bP);
    MFMA32(aQ, bQ);

    char* t_ = A2; A2 = A1; A1 = A0; A0 = t_;
    t_ = B2; B2 = B1; B1 = B0; B0 = t_;
  }
  // tail: phases NT-4 .. NT-1  (A0/B0 = buf((NT-4)%3), A1 = +1, A2 = +2)
  {
    // phase NT-4: stage NT-2, vmcnt(6), read NT-3
    STAGE(NT - 2, A2, B2);
    asm volatile("s_waitcnt vmcnt(6)" ::: "memory");
    __builtin_amdgcn_s_barrier();
    READF(A1, B1, aQ, bQ);
    MFMA32(aP, bP);
    // phase NT-3: stage NT-1, vmcnt(6), read NT-2
    STAGE(NT - 1, A0, B0);
    asm volatile("s_waitcnt vmcnt(6)" ::: "memory");
    __builtin_amdgcn_s_barrier();
    READF(A2, B2, aP, bP);
    MFMA32(aQ, bQ);
    // phase NT-2: no stage, drain all, read NT-1
    asm volatile("s_waitcnt vmcnt(0)" ::: "memory");
    __builtin_amdgcn_s_barrier();
    READF(A0, B0, aQ, bQ);
    MFMA32(aP, bP);
    // phase NT-1: compute only
    MFMA32(aQ, bQ);
  }
#undef STAGE
#undef READF
#undef MFMA32

  // ---- epilogue: 4 passes of 64x128 f32 LDS transpose -> coalesced IO ----
  // C/D layout: col=lane&15, row=(lane>>4)*4+reg  [verified m89/m91 + rounds 1-5]
  __syncthreads();
  float (*sc)[132] = (float(*)[132])smem;
  const int lr = (lane >> 4) << 2;
  const int lc = lane & 15;
  #pragma unroll
  for (int p = 0; p < 4; ++p) {
    if (wm == (p >> 1)) {
      const int ib = (p & 1) << 2;
      #pragma unroll
      for (int ii = 0; ii < 4; ++ii)
        #pragma unroll
        for (int j = 0; j < 4; ++j)
          #pragma unroll
          for (int r = 0; r < 4; ++r)
            sc[(ii << 4) + lr + r][(wn << 6) + (j << 4) + lc] = acc[ib + ii][j][r];
    }
    __syncthreads();
    #pragma unroll
    for (int rr = 0; rr < 8; ++rr) {
      const int row = (rr << 3) + (tid >> 5);
      const int col = (tid & 31) << 2;
      const f32x4 v = *(const f32x4*)&sc[row][col];
      const int gr = m0 + (p << 6) + row;
      const int gc = n0 + col;
      if constexpr (EPI == 0) {
        ushort4 o;
        o.x = f2bf(v.x); o.y = f2bf(v.y); o.z = f2bf(v.z); o.w = f2bf(v.w);
        if (n0 < D_INNER)
          *(ushort4*)&((u16*)out0)[(size_t)gr * D_INNER + gc] = o;
        else
          *(ushort4*)&((u16*)out1)[(size_t)gr * N_RES + (gc - D_INNER)] = o;
      } else if constexpr (EPI == 1) {
        const f32x4 b4 = *(const f32x4*)&bias[gc];
        const ushort4 uv = *(const ushort4*)&((const u16*)out1)[(size_t)gr * D_INNER + gc];
        float vv[4] = {v.x, v.y, v.z, v.w};
        float bb[4] = {b4.x, b4.y, b4.z, b4.w};
        u16   uu[4] = {uv.x, uv.y, uv.z, uv.w};
        u16   oo[4];
        #pragma unroll
        for (int q = 0; q < 4; ++q) {
          const float d  = vv[q] + bb[q];
          const float sp = (d > 15.f) ? d : __logf(1.f + __expf(d));
          const float sg = 1.f / (1.f + __expf(-sp));
          oo[q] = f2bf(bf2f(uu[q]) * sg);
        }
        ushort4 o; o.x = oo[0]; o.y = oo[1]; o.z = oo[2]; o.w = oo[3];
        *(ushort4*)&((u16*)out0)[(size_t)gr * D_INNER + gc] = o;
      } else {
        const ushort4 rv = *(const ushort4*)&((const u16*)out1)[(size_t)gr * N_RES + gc];
        f32x4 o;
        o.x = v.x + bf2f(rv.x); o.y = v.y + bf2f(rv.y);
        o.z = v.z + bf2f(rv.z); o.w = v.w + bf2f(rv.w);
        *(f32x4*)&((float*)out0)[(size_t)gr * N_RES + gc] = o;
      }
    }
    __syncthreads();
  }
}

// ---------------- depthwise causal conv (4 taps) ----------------
__global__ __launch_bounds__(256) void conv_kernel(
    const u16* __restrict__ u, u16* __restrict__ uc,
    const float* __restrict__ cw, const float* __restrict__ cb)
{
  const int c0 = threadIdx.x * 8;
  const int b  = blockIdx.x >> 8;
  const int t0 = (blockIdx.x & 255) << 4;
  const size_t base = (size_t)b * SEQ * D_INNER;

  float w0[8], w1[8], w2[8], w3[8], bs[8];
  #pragma unroll
  for (int j = 0; j < 8; ++j) {
    const float* wp = cw + (size_t)(c0 + j) * 4;
    w0[j] = wp[0]; w1[j] = wp[1]; w2[j] = wp[2]; w3[j] = wp[3];
    bs[j] = cb[c0 + j];
  }

  float r0[8], r1[8], r2[8];
  #pragma unroll
  for (int k = 0; k < 3; ++k) {
    const int t = t0 - 3 + k;
    float* rr = (k == 0) ? r0 : (k == 1) ? r1 : r2;
    if (t >= 0) {
      bf16x8 v = *(const bf16x8*)&u[base + (size_t)t * D_INNER + c0];
      #pragma unroll
      for (int j = 0; j < 8; ++j) rr[j] = bf2f((u16)v[j]);
    } else {
      #pragma unroll
      for (int j = 0; j < 8; ++j) rr[j] = 0.f;
    }
  }

  #pragma unroll
  for (int tt = 0; tt < 16; ++tt) {
    const size_t off = base + (size_t)(t0 + tt) * D_INNER + c0;
    bf16x8 v = *(const bf16x8*)&u[off];
    float cur[8];
    #pragma unroll
    for (int j = 0; j < 8; ++j) cur[j] = bf2f((u16)v[j]);
    bf16x8 o;
    #pragma unroll
    for (int j = 0; j < 8; ++j) {
      const float s = bs[j] + w0[j]*r0[j] + w1[j]*r1[j] + w2[j]*r2[j] + w3[j]*cur[j];
      o[j] = (short)f2bf(s);
    }
    *(bf16x8*)&uc[off] = o;
    #pragma unroll
    for (int j = 0; j < 8; ++j) { r0[j] = r1[j]; r1[j] = r2[j]; r2[j] = cur[j]; }
  }
}

// ---------------- chunked IIR scan: y[t] = 0.9 y[t-1] + 0.1 g[t] ----------------
__global__ __launch_bounds__(256) void scan_kernel(const u16* __restrict__ g, u16* __restrict__ y) {
  const int cg    = blockIdx.x & 1;
  const int chunk = (blockIdx.x >> 1) & 63;
  const int b     = blockIdx.x >> 7;
  const int c0 = cg * 1024 + threadIdx.x * 4;
  const int t0 = chunk << 6;
  const size_t base = (size_t)b * SEQ * D_INNER + c0;
  float s0 = 0.f, s1 = 0.f, s2 = 0.f, s3 = 0.f;
  const int tw = (t0 >= 96) ? t0 - 96 : 0;
  for (int t = tw; t < t0; ++t) {
    ushort4 v = *(const ushort4*)&g[base + (size_t)t * D_INNER];
    s0 = s0*0.9f + bf2f(v.x)*0.1f; s1 = s1*0.9f + bf2f(v.y)*0.1f;
    s2 = s2*0.9f + bf2f(v.z)*0.1f; s3 = s3*0.9f + bf2f(v.w)*0.1f;
  }
  for (int t = t0; t < t0 + 64; ++t) {
    ushort4 v = *(const ushort4*)&g[base + (size_t)t * D_INNER];
    s0 = s0*0.9f + bf2f(v.x)*0.1f; s1 = s1*0.9f + bf2f(v.y)*0.1f;
    s2 = s2*0.9f + bf2f(v.z)*0.1f; s3 = s3*0.9f + bf2f(v.w)*0.1f;
    ushort4 o; o.x = f2bf(s0); o.y = f2bf(s1); o.z = f2bf(s2); o.w = f2bf(s3);
    *(ushort4*)&y[base + (size_t)t * D_INNER] = o;
  }
}

extern "C" void kernel_launch(void* const* d_in, const int* in_sizes, int n_in,
                              void* d_out, int out_size, void* d_ws, size_t ws_size,
                              hipStream_t stream) {
  (void)in_sizes; (void)n_in; (void)out_size; (void)ws_size;
  const float* x  = (const float*)d_in[0];
  const float* w1 = (const float*)d_in[1];   // in_proj_w (3072,1024)
  const float* cw = (const float*)d_in[2];   // conv_w (2048,1,4)
  const float* cb = (const float*)d_in[3];   // conv_b (2048,)
  const float* w2 = (const float*)d_in[5];   // dt_proj_w (2048,2048)
  const float* db = (const float*)d_in[6];   // dt_proj_b (2048,)
  const float* w3 = (const float*)d_in[9];   // out_proj_w (1024,2048)
  // d_in[4]=x_proj_w, d_in[7]=A_log, d_in[8]=D are dead in the reference.

  char* ws = (char*)d_ws;
  u16* x_bf   = (u16*)(ws);
  u16* w1_bf  = (u16*)(ws + 33554432);
  u16* w2_bf  = (u16*)(ws + 39845888);
  u16* w3_bf  = (u16*)(ws + 48234496);
  u16* u_bf   = (u16*)(ws + 52428800);       // u, later gated
  u16* res_bf = (u16*)(ws + 119537664);
  u16* uc_bf  = (u16*)(ws + 153092096);      // uc, later y

  hipFuncSetAttribute((const void*)&gemm128<0,1024,24>, hipFuncAttributeMaxDynamicSharedMemorySize, SMEM_BYTES);
  hipFuncSetAttribute((const void*)&gemm128<1,2048,16>, hipFuncAttributeMaxDynamicSharedMemorySize, SMEM_BYTES);
  hipFuncSetAttribute((const void*)&gemm128<2,2048,8>,  hipFuncAttributeMaxDynamicSharedMemorySize, SMEM_BYTES);

  cvt_kernel<<<2048, 256, 0, stream>>>(x,  x_bf,  M_TOT * D_MODEL / 4);
  cvt_kernel<<<512, 256, 0, stream>>>(w1, w1_bf, 3072 * 1024 / 4);
  cvt_kernel<<<512, 256, 0, stream>>>(w2, w2_bf, 2048 * 2048 / 4);
  cvt_kernel<<<512, 256, 0, stream>>>(w3, w3_bf, 1024 * 2048 / 4);

  // GEMM1: (16384x1024)@(1024x3072)^T -> u / res   (64x24 tiles of 256x128)
  gemm128<0, 1024, 24><<<1536, 256, SMEM_BYTES, stream>>>(x_bf, w1_bf, u_bf, res_bf, nullptr);
  // depthwise causal conv
  conv_kernel<<<1024, 256, 0, stream>>>(u_bf, uc_bf, cw, cb);
  // GEMM2 + bias + softplus + sigmoid + gate -> gated (into u_bf)  (64x16 tiles)
  gemm128<1, 2048, 16><<<1024, 256, SMEM_BYTES, stream>>>(uc_bf, w2_bf, u_bf, uc_bf, db);
  // chunked scan -> y (into uc_bf)
  scan_kernel<<<512, 256, 0, stream>>>(u_bf, uc_bf);
  // GEMM3 + res add -> d_out (f32)  (64x8 tiles)
  gemm128<2, 2048, 8><<<512, 256, SMEM_BYTES, stream>>>(uc_bf, w3_bf, d_out, res_bf, nullptr);
}